// Round 1
// baseline (5701.551 us; speedup 1.0000x reference)
//
#include <hip/hip_runtime.h>
#include <hip/hip_bf16.h>

// GCN 3-layer forward. Layers: support = h@W ; agg = scatter_add(support[src]*ew -> dst) ; h = relu(agg + b)
// N=100000 nodes, E=1.6M edges, dims 256->128->64->64, all fp32.

#define TILE_BM 64
#define TILE_BN 64
#define TILE_BK 16

// ---------------- fp32 tiled GEMM: C[M,N] = A[M,K] @ B[K,N] ----------------
__global__ __launch_bounds__(256) void sgemm_kernel(
    const float* __restrict__ A, const float* __restrict__ B, float* __restrict__ C,
    int M, int K, int N)
{
    __shared__ float As[TILE_BK][TILE_BM];   // transposed: As[k][m]
    __shared__ float Bs[TILE_BK][TILE_BN];   // Bs[k][n]

    const int tid = threadIdx.x;
    const int tx = tid & 15;        // 16 col-groups
    const int ty = tid >> 4;        // 16 row-groups
    const int m0 = blockIdx.x * TILE_BM;
    const int n0 = blockIdx.y * TILE_BN;

    // A-tile load mapping: 64 rows x 16 k, one float4 per thread
    const int lr = tid >> 2;            // 0..63 row in tile
    const int lk = (tid & 3) << 2;      // 0,4,8,12 k in tile
    // B-tile load mapping: 16 k x 64 n, one float4 per thread
    const int br = tid >> 4;            // 0..15 k
    const int bc = (tid & 15) << 2;     // 0..60 n

    float acc[4][4];
#pragma unroll
    for (int i = 0; i < 4; ++i)
#pragma unroll
        for (int j = 0; j < 4; ++j) acc[i][j] = 0.f;

    for (int k0 = 0; k0 < K; k0 += TILE_BK) {
        float4 av = make_float4(0.f, 0.f, 0.f, 0.f);
        const int arow = m0 + lr;
        if (arow < M) av = *(const float4*)&A[(size_t)arow * K + k0 + lk];
        As[lk + 0][lr] = av.x;
        As[lk + 1][lr] = av.y;
        As[lk + 2][lr] = av.z;
        As[lk + 3][lr] = av.w;

        const float4 bv = *(const float4*)&B[(size_t)(k0 + br) * N + n0 + bc];
        *(float4*)&Bs[br][bc] = bv;

        __syncthreads();
#pragma unroll
        for (int k = 0; k < TILE_BK; ++k) {
            const float4 a4 = *(const float4*)&As[k][ty << 2];
            const float4 b4 = *(const float4*)&Bs[k][tx << 2];
            const float a[4] = {a4.x, a4.y, a4.z, a4.w};
            const float b[4] = {b4.x, b4.y, b4.z, b4.w};
#pragma unroll
            for (int i = 0; i < 4; ++i)
#pragma unroll
                for (int j = 0; j < 4; ++j) acc[i][j] += a[i] * b[j];
        }
        __syncthreads();
    }

#pragma unroll
    for (int i = 0; i < 4; ++i) {
        const int row = m0 + (ty << 2) + i;
        if (row < M) {
            float4 v = make_float4(acc[i][0], acc[i][1], acc[i][2], acc[i][3]);
            *(float4*)&C[(size_t)row * N + n0 + (tx << 2)] = v;
        }
    }
}

// ---------------- zero fill ----------------
__global__ __launch_bounds__(256) void zero_kernel(float4* __restrict__ p, int n4)
{
    const int i = blockIdx.x * 256 + threadIdx.x;
    if (i < n4) p[i] = make_float4(0.f, 0.f, 0.f, 0.f);
}

// ---------------- edge scatter: agg[dst] += support[src] * ew ----------------
// LOGT: log2(threads per edge); D = 4<<LOGT channels
template <int LOGT>
__global__ __launch_bounds__(256) void scatter_kernel(
    const float* __restrict__ S, const int* __restrict__ src, const int* __restrict__ dst,
    const float* __restrict__ ew, float* __restrict__ agg, int E)
{
    const int TPE = 1 << LOGT;
    const int D = TPE * 4;
    const int gid = blockIdx.x * 256 + threadIdx.x;
    const int e = gid >> LOGT;
    if (e >= E) return;
    const int c4 = (gid & (TPE - 1)) << 2;

    const int s = src[e];
    const int d = dst[e];
    const float w = ew[e];

    const float4 v = *(const float4*)&S[(size_t)s * D + c4];
    float* p = &agg[(size_t)d * D + c4];
    atomicAdd(p + 0, v.x * w);
    atomicAdd(p + 1, v.y * w);
    atomicAdd(p + 2, v.z * w);
    atomicAdd(p + 3, v.w * w);
}

// ---------------- bias (+ optional relu), float4-wide ----------------
template <int D, bool RELU>
__global__ __launch_bounds__(256) void bias_act_kernel(
    const float* __restrict__ agg, const float* __restrict__ bias,
    float* __restrict__ out, int total4)
{
    const int i = blockIdx.x * 256 + threadIdx.x;
    if (i >= total4) return;
    const int c4 = (i & (D / 4 - 1)) << 2;
    float4 v = *(const float4*)&agg[(size_t)i * 4];
    const float4 b = *(const float4*)&bias[c4];
    v.x += b.x; v.y += b.y; v.z += b.z; v.w += b.w;
    if (RELU) {
        v.x = fmaxf(v.x, 0.f); v.y = fmaxf(v.y, 0.f);
        v.z = fmaxf(v.z, 0.f); v.w = fmaxf(v.w, 0.f);
    }
    *(float4*)&out[(size_t)i * 4] = v;
}

extern "C" void kernel_launch(void* const* d_in, const int* in_sizes, int n_in,
                              void* d_out, int out_size, void* d_ws, size_t ws_size,
                              hipStream_t stream)
{
    const float* x    = (const float*)d_in[0];
    const int*   esrc = (const int*)  d_in[1];
    const int*   edst = (const int*)  d_in[2];
    const float* ew   = (const float*)d_in[3];
    const float* W1   = (const float*)d_in[4];
    const float* b1   = (const float*)d_in[5];
    const float* W2   = (const float*)d_in[6];
    const float* b2   = (const float*)d_in[7];
    const float* W3   = (const float*)d_in[8];
    const float* b3   = (const float*)d_in[9];

    const int N = in_sizes[0] / 256;   // 100000 nodes
    const int E = in_sizes[1];         // 1.6M edges

    float* S   = (float*)d_ws;               // support buffer: N*128 floats
    float* AGG = S + (size_t)N * 128;        // agg / h buffer:  N*128 floats
    float* out = (float*)d_out;

    const dim3 blk(256);
    const int mblocks = (N + TILE_BM - 1) / TILE_BM;

    // ---- layer 1: 256 -> 128 ----
    sgemm_kernel<<<dim3(mblocks, 2), blk, 0, stream>>>(x, W1, S, N, 256, 128);
    {
        const int n4 = N * 128 / 4;
        zero_kernel<<<(n4 + 255) / 256, blk, 0, stream>>>((float4*)AGG, n4);
    }
    scatter_kernel<5><<<((E * 32) + 255) / 256, blk, 0, stream>>>(S, esrc, edst, ew, AGG, E);
    bias_act_kernel<128, true><<<((N * 32) + 255) / 256, blk, 0, stream>>>(AGG, b1, AGG, N * 32);

    // ---- layer 2: 128 -> 64 ----
    sgemm_kernel<<<dim3(mblocks, 1), blk, 0, stream>>>(AGG, W2, S, N, 128, 64);
    {
        const int n4 = N * 64 / 4;
        zero_kernel<<<(n4 + 255) / 256, blk, 0, stream>>>((float4*)AGG, n4);
    }
    scatter_kernel<4><<<((E * 16) + 255) / 256, blk, 0, stream>>>(S, esrc, edst, ew, AGG, E);
    bias_act_kernel<64, true><<<((N * 16) + 255) / 256, blk, 0, stream>>>(AGG, b2, AGG, N * 16);

    // ---- layer 3: 64 -> 64 ----
    sgemm_kernel<<<dim3(mblocks, 1), blk, 0, stream>>>(AGG, W3, S, N, 64, 64);
    {
        const int n4 = N * 64 / 4;
        zero_kernel<<<(n4 + 255) / 256, blk, 0, stream>>>((float4*)AGG, n4);
    }
    scatter_kernel<4><<<((E * 16) + 255) / 256, blk, 0, stream>>>(S, esrc, edst, ew, AGG, E);
    bias_act_kernel<64, false><<<((N * 16) + 255) / 256, blk, 0, stream>>>(AGG, b3, out, N * 16);
}

// Round 2
// 705.808 us; speedup vs baseline: 8.0780x; 8.0780x over previous
//
#include <hip/hip_runtime.h>
#include <hip/hip_bf16.h>

// GCN 3-layer forward, CSR-gather formulation (no fp32 atomics).
// Per layer: S = H @ W (dense GEMM); H' = relu( gather_sum_{e: dst=i} w_e * S[src_e] + b )
// CSR (by dst) is rebuilt on-device every call: hist -> 3-pass scan -> fill.

#define TILE_BM 64
#define TILE_BN 64
#define TILE_BK 16

// ---------------- fp32 tiled GEMM: C[M,N] = A[M,K] @ B[K,N] ----------------
__global__ __launch_bounds__(256) void sgemm_kernel(
    const float* __restrict__ A, const float* __restrict__ B, float* __restrict__ C,
    int M, int K, int N)
{
    __shared__ float As[TILE_BK][TILE_BM];   // transposed: As[k][m]
    __shared__ float Bs[TILE_BK][TILE_BN];   // Bs[k][n]

    const int tid = threadIdx.x;
    const int tx = tid & 15;
    const int ty = tid >> 4;
    const int m0 = blockIdx.x * TILE_BM;
    const int n0 = blockIdx.y * TILE_BN;

    const int lr = tid >> 2;            // 0..63 row in A-tile
    const int lk = (tid & 3) << 2;      // 0,4,8,12 k in A-tile
    const int br = tid >> 4;            // 0..15 k in B-tile
    const int bc = (tid & 15) << 2;     // 0..60 n in B-tile

    float acc[4][4];
#pragma unroll
    for (int i = 0; i < 4; ++i)
#pragma unroll
        for (int j = 0; j < 4; ++j) acc[i][j] = 0.f;

    for (int k0 = 0; k0 < K; k0 += TILE_BK) {
        float4 av = make_float4(0.f, 0.f, 0.f, 0.f);
        const int arow = m0 + lr;
        if (arow < M) av = *(const float4*)&A[(size_t)arow * K + k0 + lk];
        As[lk + 0][lr] = av.x;
        As[lk + 1][lr] = av.y;
        As[lk + 2][lr] = av.z;
        As[lk + 3][lr] = av.w;

        const float4 bv = *(const float4*)&B[(size_t)(k0 + br) * N + n0 + bc];
        *(float4*)&Bs[br][bc] = bv;

        __syncthreads();
#pragma unroll
        for (int k = 0; k < TILE_BK; ++k) {
            const float4 a4 = *(const float4*)&As[k][ty << 2];
            const float4 b4 = *(const float4*)&Bs[k][tx << 2];
            const float a[4] = {a4.x, a4.y, a4.z, a4.w};
            const float b[4] = {b4.x, b4.y, b4.z, b4.w};
#pragma unroll
            for (int i = 0; i < 4; ++i)
#pragma unroll
                for (int j = 0; j < 4; ++j) acc[i][j] += a[i] * b[j];
        }
        __syncthreads();
    }

#pragma unroll
    for (int i = 0; i < 4; ++i) {
        const int row = m0 + (ty << 2) + i;
        if (row < M) {
            float4 v = make_float4(acc[i][0], acc[i][1], acc[i][2], acc[i][3]);
            *(float4*)&C[(size_t)row * N + n0 + (tx << 2)] = v;
        }
    }
}

// ---------------- CSR build ----------------
__global__ __launch_bounds__(256) void zero_int_kernel(int* __restrict__ p, int n)
{
    const int i = blockIdx.x * 256 + threadIdx.x;
    if (i < n) p[i] = 0;
}

__global__ __launch_bounds__(256) void hist_kernel(
    const int* __restrict__ dst, int* __restrict__ deg, int E)
{
    const int e = blockIdx.x * 256 + threadIdx.x;
    if (e < E) atomicAdd(&deg[dst[e]], 1);
}

// pass 1: per-block exclusive scan of deg -> offs, block totals -> bsum
__global__ __launch_bounds__(256) void scan1_kernel(
    const int* __restrict__ deg, int* __restrict__ offs, int* __restrict__ bsum, int n)
{
    __shared__ int tmp[256];
    const int i = blockIdx.x * 256 + threadIdx.x;
    const int v = (i < n) ? deg[i] : 0;
    tmp[threadIdx.x] = v;
    __syncthreads();
#pragma unroll
    for (int d = 1; d < 256; d <<= 1) {
        const int t = (threadIdx.x >= d) ? tmp[threadIdx.x - d] : 0;
        __syncthreads();
        tmp[threadIdx.x] += t;
        __syncthreads();
    }
    if (i < n) offs[i] = tmp[threadIdx.x] - v;   // exclusive
    if (threadIdx.x == 255) bsum[blockIdx.x] = tmp[255];
}

// pass 2: single-block exclusive scan of block sums (nb <= 512)
__global__ __launch_bounds__(512) void scan2_kernel(int* __restrict__ bsum, int nb)
{
    __shared__ int tmp[512];
    const int v = (threadIdx.x < nb) ? bsum[threadIdx.x] : 0;
    tmp[threadIdx.x] = v;
    __syncthreads();
#pragma unroll
    for (int d = 1; d < 512; d <<= 1) {
        const int t = ((int)threadIdx.x >= d) ? tmp[threadIdx.x - d] : 0;
        __syncthreads();
        tmp[threadIdx.x] += t;
        __syncthreads();
    }
    if ((int)threadIdx.x < nb) bsum[threadIdx.x] = tmp[threadIdx.x] - v;  // exclusive
}

// pass 3: add block base; init cursor; set offs[n] = E
__global__ __launch_bounds__(256) void scan3_kernel(
    int* __restrict__ offs, const int* __restrict__ bsum, int* __restrict__ cursor,
    int n, int E)
{
    const int i = blockIdx.x * 256 + threadIdx.x;
    if (i < n) {
        const int o = offs[i] + bsum[blockIdx.x];
        offs[i] = o;
        cursor[i] = o;
    }
    if (i == 0) offs[n] = E;
}

__global__ __launch_bounds__(256) void fill_kernel(
    const int* __restrict__ src, const int* __restrict__ dst, const float* __restrict__ ew,
    int* __restrict__ cursor, int* __restrict__ cols, float* __restrict__ cw, int E)
{
    const int e = blockIdx.x * 256 + threadIdx.x;
    if (e >= E) return;
    const int pos = atomicAdd(&cursor[dst[e]], 1);
    cols[pos] = src[e];
    cw[pos] = ew[e];
}

// ---------------- fused gather-aggregate + bias + relu ----------------
// D channels per node, TPN = D/4 threads per node (LOGT = log2(TPN))
template <int D, int LOGT, bool RELU>
__global__ __launch_bounds__(256) void gather_agg_kernel(
    const float* __restrict__ S, const int* __restrict__ offs,
    const int* __restrict__ cols, const float* __restrict__ cw,
    const float* __restrict__ bias, float* __restrict__ out, int N)
{
    const int TPN = 1 << LOGT;
    const int gid = blockIdx.x * 256 + threadIdx.x;
    const int node = gid >> LOGT;
    if (node >= N) return;
    const int c4 = (gid & (TPN - 1)) << 2;

    const int j0 = offs[node];
    const int j1 = offs[node + 1];

    float4 acc = make_float4(0.f, 0.f, 0.f, 0.f);
    for (int j = j0; j < j1; ++j) {
        const int s = cols[j];          // same addr across TPN lanes -> broadcast
        const float w = cw[j];
        const float4 v = *(const float4*)&S[(size_t)s * D + c4];
        acc.x += w * v.x;
        acc.y += w * v.y;
        acc.z += w * v.z;
        acc.w += w * v.w;
    }
    const float4 b = *(const float4*)&bias[c4];
    acc.x += b.x; acc.y += b.y; acc.z += b.z; acc.w += b.w;
    if (RELU) {
        acc.x = fmaxf(acc.x, 0.f); acc.y = fmaxf(acc.y, 0.f);
        acc.z = fmaxf(acc.z, 0.f); acc.w = fmaxf(acc.w, 0.f);
    }
    *(float4*)&out[(size_t)node * D + c4] = acc;
}

extern "C" void kernel_launch(void* const* d_in, const int* in_sizes, int n_in,
                              void* d_out, int out_size, void* d_ws, size_t ws_size,
                              hipStream_t stream)
{
    const float* x    = (const float*)d_in[0];
    const int*   esrc = (const int*)  d_in[1];
    const int*   edst = (const int*)  d_in[2];
    const float* ew   = (const float*)d_in[3];
    const float* W1   = (const float*)d_in[4];
    const float* b1   = (const float*)d_in[5];
    const float* W2   = (const float*)d_in[6];
    const float* b2   = (const float*)d_in[7];
    const float* W3   = (const float*)d_in[8];
    const float* b3   = (const float*)d_in[9];

    const int N = in_sizes[0] / 256;   // 100000
    const int E = in_sizes[1];         // 1600000

    // workspace layout
    float* A   = (float*)d_ws;                 // N*128 (support S)
    float* B   = A + (size_t)N * 128;          // N*128 (hidden H)
    int* deg    = (int*)(B + (size_t)N * 128); // N
    int* offs   = deg + N;                     // N+1 (padded to N+4)
    int* cursor = offs + N + 4;                // N
    int* bsum   = cursor + N;                  // 512
    int* cols   = bsum + 512;                  // E
    float* cw   = (float*)(cols + E);          // E
    float* out  = (float*)d_out;

    const dim3 blk(256);
    const int nblkN = (N + 255) / 256;         // 391
    const int nblkE = (E + 255) / 256;
    const int mblocks = (N + TILE_BM - 1) / TILE_BM;

    // ---- build CSR by dst ----
    zero_int_kernel<<<nblkN, blk, 0, stream>>>(deg, N);
    hist_kernel<<<nblkE, blk, 0, stream>>>(edst, deg, E);
    scan1_kernel<<<nblkN, blk, 0, stream>>>(deg, offs, bsum, N);
    scan2_kernel<<<1, 512, 0, stream>>>(bsum, nblkN);
    scan3_kernel<<<nblkN, blk, 0, stream>>>(offs, bsum, cursor, N, E);
    fill_kernel<<<nblkE, blk, 0, stream>>>(esrc, edst, ew, cursor, cols, cw, E);

    // ---- layer 1: 256 -> 128 ----
    sgemm_kernel<<<dim3(mblocks, 2), blk, 0, stream>>>(x, W1, A, N, 256, 128);
    gather_agg_kernel<128, 5, true><<<((N * 32) + 255) / 256, blk, 0, stream>>>(
        A, offs, cols, cw, b1, B, N);

    // ---- layer 2: 128 -> 64 ----
    sgemm_kernel<<<dim3(mblocks, 1), blk, 0, stream>>>(B, W2, A, N, 128, 64);
    gather_agg_kernel<64, 4, true><<<((N * 16) + 255) / 256, blk, 0, stream>>>(
        A, offs, cols, cw, b2, B, N);

    // ---- layer 3: 64 -> 64 ----
    sgemm_kernel<<<dim3(mblocks, 1), blk, 0, stream>>>(B, W3, A, N, 64, 64);
    gather_agg_kernel<64, 4, false><<<((N * 16) + 255) / 256, blk, 0, stream>>>(
        A, offs, cols, cw, b3, out, N);
}

// Round 3
// 600.635 us; speedup vs baseline: 9.4925x; 1.1751x over previous
//
#include <hip/hip_runtime.h>
#include <hip/hip_bf16.h>

// GCN 3-layer forward, CSR-gather formulation.
// Round 3: support buffer S stored as bf16 (GEMM epilogue converts), gather reads
// 8 bf16 channels/lane (16B), index broadcast via __shfl chunks (independent row loads).

#define TILE_BM 64
#define TILE_BN 64
#define TILE_BK 16

__device__ __forceinline__ unsigned short f2bf(float f) {
    unsigned int u = __float_as_uint(f);
    unsigned int r = (u + 0x7fffu + ((u >> 16) & 1u)) >> 16;   // RNE
    return (unsigned short)r;
}

// ---------------- fp32 tiled GEMM: C[M,N] = A[M,K] @ B[K,N], C stored bf16 ----------------
__global__ __launch_bounds__(256) void sgemm_bf16out_kernel(
    const float* __restrict__ A, const float* __restrict__ B, unsigned short* __restrict__ C,
    int M, int K, int N)
{
    __shared__ float As[TILE_BK][TILE_BM];   // transposed: As[k][m]
    __shared__ float Bs[TILE_BK][TILE_BN];

    const int tid = threadIdx.x;
    const int tx = tid & 15;
    const int ty = tid >> 4;
    const int m0 = blockIdx.x * TILE_BM;
    const int n0 = blockIdx.y * TILE_BN;

    const int lr = tid >> 2;
    const int lk = (tid & 3) << 2;
    const int br = tid >> 4;
    const int bc = (tid & 15) << 2;

    float acc[4][4];
#pragma unroll
    for (int i = 0; i < 4; ++i)
#pragma unroll
        for (int j = 0; j < 4; ++j) acc[i][j] = 0.f;

    for (int k0 = 0; k0 < K; k0 += TILE_BK) {
        float4 av = make_float4(0.f, 0.f, 0.f, 0.f);
        const int arow = m0 + lr;
        if (arow < M) av = *(const float4*)&A[(size_t)arow * K + k0 + lk];
        As[lk + 0][lr] = av.x;
        As[lk + 1][lr] = av.y;
        As[lk + 2][lr] = av.z;
        As[lk + 3][lr] = av.w;

        const float4 bv = *(const float4*)&B[(size_t)(k0 + br) * N + n0 + bc];
        *(float4*)&Bs[br][bc] = bv;

        __syncthreads();
#pragma unroll
        for (int k = 0; k < TILE_BK; ++k) {
            const float4 a4 = *(const float4*)&As[k][ty << 2];
            const float4 b4 = *(const float4*)&Bs[k][tx << 2];
            const float a[4] = {a4.x, a4.y, a4.z, a4.w};
            const float b[4] = {b4.x, b4.y, b4.z, b4.w};
#pragma unroll
            for (int i = 0; i < 4; ++i)
#pragma unroll
                for (int j = 0; j < 4; ++j) acc[i][j] += a[i] * b[j];
        }
        __syncthreads();
    }

#pragma unroll
    for (int i = 0; i < 4; ++i) {
        const int row = m0 + (ty << 2) + i;
        if (row < M) {
            ushort4 v;
            v.x = f2bf(acc[i][0]); v.y = f2bf(acc[i][1]);
            v.z = f2bf(acc[i][2]); v.w = f2bf(acc[i][3]);
            *(ushort4*)&C[(size_t)row * N + n0 + (tx << 2)] = v;
        }
    }
}

// ---------------- CSR build ----------------
__global__ __launch_bounds__(256) void zero_int_kernel(int* __restrict__ p, int n)
{
    const int i = blockIdx.x * 256 + threadIdx.x;
    if (i < n) p[i] = 0;
}

__global__ __launch_bounds__(256) void hist_kernel(
    const int* __restrict__ dst, int* __restrict__ deg, int E)
{
    const int e = blockIdx.x * 256 + threadIdx.x;
    if (e < E) atomicAdd(&deg[dst[e]], 1);
}

__global__ __launch_bounds__(256) void scan1_kernel(
    const int* __restrict__ deg, int* __restrict__ offs, int* __restrict__ bsum, int n)
{
    __shared__ int tmp[256];
    const int i = blockIdx.x * 256 + threadIdx.x;
    const int v = (i < n) ? deg[i] : 0;
    tmp[threadIdx.x] = v;
    __syncthreads();
#pragma unroll
    for (int d = 1; d < 256; d <<= 1) {
        const int t = (threadIdx.x >= d) ? tmp[threadIdx.x - d] : 0;
        __syncthreads();
        tmp[threadIdx.x] += t;
        __syncthreads();
    }
    if (i < n) offs[i] = tmp[threadIdx.x] - v;
    if (threadIdx.x == 255) bsum[blockIdx.x] = tmp[255];
}

__global__ __launch_bounds__(512) void scan2_kernel(int* __restrict__ bsum, int nb)
{
    __shared__ int tmp[512];
    const int v = ((int)threadIdx.x < nb) ? bsum[threadIdx.x] : 0;
    tmp[threadIdx.x] = v;
    __syncthreads();
#pragma unroll
    for (int d = 1; d < 512; d <<= 1) {
        const int t = ((int)threadIdx.x >= d) ? tmp[threadIdx.x - d] : 0;
        __syncthreads();
        tmp[threadIdx.x] += t;
        __syncthreads();
    }
    if ((int)threadIdx.x < nb) bsum[threadIdx.x] = tmp[threadIdx.x] - v;
}

__global__ __launch_bounds__(256) void scan3_kernel(
    int* __restrict__ offs, const int* __restrict__ bsum, int* __restrict__ cursor,
    int n, int E)
{
    const int i = blockIdx.x * 256 + threadIdx.x;
    if (i < n) {
        const int o = offs[i] + bsum[blockIdx.x];
        offs[i] = o;
        cursor[i] = o;
    }
    if (i == 0) offs[n] = E;
}

__global__ __launch_bounds__(256) void fill_kernel(
    const int* __restrict__ src, const int* __restrict__ dst, const float* __restrict__ ew,
    int* __restrict__ cursor, int* __restrict__ cols, float* __restrict__ cw, int E)
{
    const int e = blockIdx.x * 256 + threadIdx.x;
    if (e >= E) return;
    const int pos = atomicAdd(&cursor[dst[e]], 1);
    cols[pos] = src[e];
    cw[pos] = ew[e];
}

// ---------------- fused gather-aggregate (bf16 S) + bias + relu (fp32 out) ----------------
// D channels/node; TPN = D/8 lanes per node; each lane owns 8 channels (16B bf16).
template <int D, int LOGT, bool RELU>
__global__ __launch_bounds__(256) void gather_agg_kernel(
    const unsigned short* __restrict__ S, const int* __restrict__ offs,
    const int* __restrict__ cols, const float* __restrict__ cw,
    const float* __restrict__ bias, float* __restrict__ out, int N)
{
    const int TPN = 1 << LOGT;
    const int gid = blockIdx.x * 256 + threadIdx.x;
    const int node = gid >> LOGT;
    if (node >= N) return;
    const int lane = gid & (TPN - 1);
    const int c8 = lane << 3;

    const int j0 = offs[node];
    const int j1 = offs[node + 1];

    float acc[8];
#pragma unroll
    for (int c = 0; c < 8; ++c) acc[c] = 0.f;

    for (int jb = j0; jb < j1; jb += TPN) {
        const int j = jb + lane;
        int myc = 0;
        float myw = 0.f;
        if (j < j1) { myc = cols[j]; myw = cw[j]; }
        const int cnt = min(TPN, j1 - jb);
        for (int t = 0; t < cnt; ++t) {
            const int s = __shfl(myc, t, TPN);
            const float w = __shfl(myw, t, TPN);
            const uint4 v = *(const uint4*)&S[(size_t)s * D + c8];
#pragma unroll
            for (int q = 0; q < 4; ++q) {
                const unsigned int u = (&v.x)[q];
                const float lo = __uint_as_float(u << 16);
                const float hi = __uint_as_float(u & 0xffff0000u);
                acc[q * 2 + 0] += w * lo;
                acc[q * 2 + 1] += w * hi;
            }
        }
    }

#pragma unroll
    for (int c = 0; c < 8; ++c) {
        float v = acc[c] + bias[c8 + c];
        if (RELU) v = fmaxf(v, 0.f);
        acc[c] = v;
    }
    float4* op = (float4*)&out[(size_t)node * D + c8];
    op[0] = make_float4(acc[0], acc[1], acc[2], acc[3]);
    op[1] = make_float4(acc[4], acc[5], acc[6], acc[7]);
}

extern "C" void kernel_launch(void* const* d_in, const int* in_sizes, int n_in,
                              void* d_out, int out_size, void* d_ws, size_t ws_size,
                              hipStream_t stream)
{
    const float* x    = (const float*)d_in[0];
    const int*   esrc = (const int*)  d_in[1];
    const int*   edst = (const int*)  d_in[2];
    const float* ew   = (const float*)d_in[3];
    const float* W1   = (const float*)d_in[4];
    const float* b1   = (const float*)d_in[5];
    const float* W2   = (const float*)d_in[6];
    const float* b2   = (const float*)d_in[7];
    const float* W3   = (const float*)d_in[8];
    const float* b3   = (const float*)d_in[9];

    const int N = in_sizes[0] / 256;   // 100000
    const int E = in_sizes[1];         // 1600000

    // workspace layout
    unsigned short* Sb = (unsigned short*)d_ws;       // bf16 support: N*128
    float* H   = (float*)(Sb + (size_t)N * 128);      // fp32 hidden: N*128
    int* deg    = (int*)(H + (size_t)N * 128);        // N
    int* offs   = deg + N;                            // N+1 (pad 4)
    int* cursor = offs + N + 4;                       // N
    int* bsum   = cursor + N;                         // 512
    int* cols   = bsum + 512;                         // E
    float* cw   = (float*)(cols + E);                 // E
    float* out  = (float*)d_out;

    const dim3 blk(256);
    const int nblkN = (N + 255) / 256;
    const int nblkE = (E + 255) / 256;
    const int mblocks = (N + TILE_BM - 1) / TILE_BM;

    // ---- build CSR by dst ----
    zero_int_kernel<<<nblkN, blk, 0, stream>>>(deg, N);
    hist_kernel<<<nblkE, blk, 0, stream>>>(edst, deg, E);
    scan1_kernel<<<nblkN, blk, 0, stream>>>(deg, offs, bsum, N);
    scan2_kernel<<<1, 512, 0, stream>>>(bsum, nblkN);
    scan3_kernel<<<nblkN, blk, 0, stream>>>(offs, bsum, cursor, N, E);
    fill_kernel<<<nblkE, blk, 0, stream>>>(esrc, edst, ew, cursor, cols, cw, E);

    // ---- layer 1: 256 -> 128 ----
    sgemm_bf16out_kernel<<<dim3(mblocks, 2), blk, 0, stream>>>(x, W1, Sb, N, 256, 128);
    gather_agg_kernel<128, 4, true><<<((N * 16) + 255) / 256, blk, 0, stream>>>(
        Sb, offs, cols, cw, b1, H, N);

    // ---- layer 2: 128 -> 64 ----
    sgemm_bf16out_kernel<<<dim3(mblocks, 1), blk, 0, stream>>>(H, W2, Sb, N, 128, 64);
    gather_agg_kernel<64, 3, true><<<((N * 8) + 255) / 256, blk, 0, stream>>>(
        Sb, offs, cols, cw, b2, H, N);

    // ---- layer 3: 64 -> 64 ----
    sgemm_bf16out_kernel<<<dim3(mblocks, 1), blk, 0, stream>>>(H, W3, Sb, N, 64, 64);
    gather_agg_kernel<64, 3, false><<<((N * 8) + 255) / 256, blk, 0, stream>>>(
        Sb, offs, cols, cw, b3, out, N);
}

// Round 4
// 542.821 us; speedup vs baseline: 10.5036x; 1.1065x over previous
//
#include <hip/hip_runtime.h>
#include <hip/hip_bf16.h>

// GCN 3-layer forward. Round 4:
//  - GEMMs via bf16 MFMA 16x16x32 (A converted fp32->bf16 during LDS staging,
//    W pre-transposed to [N][K] bf16 once per call).
//  - CSR fill packs (src,weight) as uint2 -> one 8B scattered store per edge.
//  - Gather-aggregate reads bf16 support rows (16B/lane), fp32 accum, fused bias/relu.

__device__ __forceinline__ unsigned short f2bf(float f) {
    unsigned int u = __float_as_uint(f);
    unsigned int r = (u + 0x7fffu + ((u >> 16) & 1u)) >> 16;   // RNE
    return (unsigned short)r;
}

using frag_ab = __attribute__((ext_vector_type(8))) short;   // 8 bf16
using frag_cd = __attribute__((ext_vector_type(4))) float;   // 4 fp32

// ---------------- MFMA GEMM: C[M,BN](bf16) = A[M,K](fp32) @ W_T[BN,K](bf16)^T ----------------
// BM=64 rows/block, BK=64, 4 waves: wave w owns rows [w*16, w*16+16).
template <int BN>
__global__ __launch_bounds__(256) void mfma_gemm_kernel(
    const float* __restrict__ A, const unsigned short* __restrict__ WT,
    unsigned short* __restrict__ C, int M, int K)
{
    constexpr int BM = 64, BK = 64;
    constexpr int LDA = BK + 8;                    // +16B pad: 2-way LDS conflict (free)
    __shared__ unsigned short As[BM * LDA];
    __shared__ unsigned short Bs[BN * LDA];

    const int tid = threadIdx.x;
    const int wave = tid >> 6;
    const int lane = tid & 63;
    const int quad = lane >> 4;
    const int l16 = lane & 15;
    const int m0 = blockIdx.x * BM;

    frag_cd acc[BN / 16];
#pragma unroll
    for (int f = 0; f < BN / 16; ++f) acc[f] = (frag_cd){0.f, 0.f, 0.f, 0.f};

    for (int k0 = 0; k0 < K; k0 += BK) {
        // stage A tile (64x64 fp32 -> bf16): 4 float4 per thread
#pragma unroll
        for (int i = 0; i < 4; ++i) {
            const int linear = (i * 256 + tid) * 4;
            const int r = linear >> 6;
            const int c = linear & 63;
            const int row = m0 + r;
            float4 v = make_float4(0.f, 0.f, 0.f, 0.f);
            if (row < M) v = *(const float4*)&A[(size_t)row * K + k0 + c];
            ushort4 u;
            u.x = f2bf(v.x); u.y = f2bf(v.y); u.z = f2bf(v.z); u.w = f2bf(v.w);
            *(ushort4*)&As[r * LDA + c] = u;
        }
        // stage B tile (BN x 64 bf16): BN/32 uint4 per thread
#pragma unroll
        for (int i = 0; i < BN / 32; ++i) {
            const int linear = (i * 256 + tid) * 8;
            const int n = linear >> 6;
            const int c = linear & 63;
            const uint4 u = *(const uint4*)&WT[(size_t)n * K + k0 + c];
            *(uint4*)&Bs[n * LDA + c] = u;
        }
        __syncthreads();

#pragma unroll
        for (int ks = 0; ks < 2; ++ks) {
            const int kk = ks * 32 + quad * 8;
            const frag_ab a = *(const frag_ab*)&As[(wave * 16 + l16) * LDA + kk];
#pragma unroll
            for (int f = 0; f < BN / 16; ++f) {
                const frag_ab b = *(const frag_ab*)&Bs[(f * 16 + l16) * LDA + kk];
                acc[f] = __builtin_amdgcn_mfma_f32_16x16x32_bf16(a, b, acc[f], 0, 0, 0);
            }
        }
        __syncthreads();
    }

    // epilogue: row = m0 + wave*16 + quad*4 + r ; col = f*16 + l16
#pragma unroll
    for (int f = 0; f < BN / 16; ++f) {
#pragma unroll
        for (int r = 0; r < 4; ++r) {
            const int row = m0 + wave * 16 + quad * 4 + r;
            if (row < M) C[(size_t)row * BN + f * 16 + l16] = f2bf(acc[f][r]);
        }
    }
}

// ---------------- weight transpose+convert: W[K,N] fp32 -> WT[N,K] bf16, all 3 layers ----------------
__global__ __launch_bounds__(256) void wt_kernel(
    const float* __restrict__ W1, const float* __restrict__ W2, const float* __restrict__ W3,
    unsigned short* __restrict__ WT1, unsigned short* __restrict__ WT2, unsigned short* __restrict__ WT3)
{
    const int i = blockIdx.x * 256 + threadIdx.x;   // over 45056 total elements
    const float* W; unsigned short* WT; int K, N, j;
    if (i < 32768)      { W = W1; WT = WT1; K = 256; N = 128; j = i; }
    else if (i < 40960) { W = W2; WT = WT2; K = 128; N = 64;  j = i - 32768; }
    else if (i < 45056) { W = W3; WT = WT3; K = 64;  N = 64;  j = i - 40960; }
    else return;
    const int n = j / K, k = j % K;
    WT[j] = f2bf(W[k * N + n]);
}

// ---------------- CSR build ----------------
__global__ __launch_bounds__(256) void zero_int_kernel(int* __restrict__ p, int n)
{
    const int i = blockIdx.x * 256 + threadIdx.x;
    if (i < n) p[i] = 0;
}

__global__ __launch_bounds__(256) void hist_kernel(
    const int* __restrict__ dst, int* __restrict__ deg, int E)
{
    const int e = blockIdx.x * 256 + threadIdx.x;
    if (e < E) atomicAdd(&deg[dst[e]], 1);
}

__global__ __launch_bounds__(256) void scan1_kernel(
    const int* __restrict__ deg, int* __restrict__ offs, int* __restrict__ bsum, int n)
{
    __shared__ int tmp[256];
    const int i = blockIdx.x * 256 + threadIdx.x;
    const int v = (i < n) ? deg[i] : 0;
    tmp[threadIdx.x] = v;
    __syncthreads();
#pragma unroll
    for (int d = 1; d < 256; d <<= 1) {
        const int t = (threadIdx.x >= d) ? tmp[threadIdx.x - d] : 0;
        __syncthreads();
        tmp[threadIdx.x] += t;
        __syncthreads();
    }
    if (i < n) offs[i] = tmp[threadIdx.x] - v;
    if (threadIdx.x == 255) bsum[blockIdx.x] = tmp[255];
}

__global__ __launch_bounds__(512) void scan2_kernel(int* __restrict__ bsum, int nb)
{
    __shared__ int tmp[512];
    const int v = ((int)threadIdx.x < nb) ? bsum[threadIdx.x] : 0;
    tmp[threadIdx.x] = v;
    __syncthreads();
#pragma unroll
    for (int d = 1; d < 512; d <<= 1) {
        const int t = ((int)threadIdx.x >= d) ? tmp[threadIdx.x - d] : 0;
        __syncthreads();
        tmp[threadIdx.x] += t;
        __syncthreads();
    }
    if ((int)threadIdx.x < nb) bsum[threadIdx.x] = tmp[threadIdx.x] - v;
}

__global__ __launch_bounds__(256) void scan3_kernel(
    int* __restrict__ offs, const int* __restrict__ bsum, int* __restrict__ cursor,
    int n, int E)
{
    const int i = blockIdx.x * 256 + threadIdx.x;
    if (i < n) {
        const int o = offs[i] + bsum[blockIdx.x];
        offs[i] = o;
        cursor[i] = o;
    }
    if (i == 0) offs[n] = E;
}

// packed fill: one 8B scattered store per edge
__global__ __launch_bounds__(256) void fill_kernel(
    const int* __restrict__ src, const int* __restrict__ dst, const float* __restrict__ ew,
    int* __restrict__ cursor, uint2* __restrict__ ecsr, int E)
{
    const int e = blockIdx.x * 256 + threadIdx.x;
    if (e >= E) return;
    const int pos = atomicAdd(&cursor[dst[e]], 1);
    ecsr[pos] = make_uint2((unsigned)src[e], __float_as_uint(ew[e]));
}

// ---------------- fused gather-aggregate (bf16 S) + bias + relu (fp32 out) ----------------
template <int D, int LOGT, bool RELU>
__global__ __launch_bounds__(256) void gather_agg_kernel(
    const unsigned short* __restrict__ S, const int* __restrict__ offs,
    const uint2* __restrict__ ecsr,
    const float* __restrict__ bias, float* __restrict__ out, int N)
{
    const int TPN = 1 << LOGT;
    const int gid = blockIdx.x * 256 + threadIdx.x;
    const int node = gid >> LOGT;
    if (node >= N) return;
    const int lane = gid & (TPN - 1);
    const int c8 = lane << 3;

    const int j0 = offs[node];
    const int j1 = offs[node + 1];

    float acc[8];
#pragma unroll
    for (int c = 0; c < 8; ++c) acc[c] = 0.f;

    for (int jb = j0; jb < j1; jb += TPN) {
        const int j = jb + lane;
        int myc = 0;
        float myw = 0.f;
        if (j < j1) {
            const uint2 p = ecsr[j];
            myc = (int)p.x;
            myw = __uint_as_float(p.y);
        }
        const int cnt = min(TPN, j1 - jb);
        for (int t = 0; t < cnt; ++t) {
            const int s = __shfl(myc, t, TPN);
            const float w = __shfl(myw, t, TPN);
            const uint4 v = *(const uint4*)&S[(size_t)s * D + c8];
#pragma unroll
            for (int q = 0; q < 4; ++q) {
                const unsigned int u = (&v.x)[q];
                const float lo = __uint_as_float(u << 16);
                const float hi = __uint_as_float(u & 0xffff0000u);
                acc[q * 2 + 0] += w * lo;
                acc[q * 2 + 1] += w * hi;
            }
        }
    }

#pragma unroll
    for (int c = 0; c < 8; ++c) {
        float v = acc[c] + bias[c8 + c];
        if (RELU) v = fmaxf(v, 0.f);
        acc[c] = v;
    }
    float4* op = (float4*)&out[(size_t)node * D + c8];
    op[0] = make_float4(acc[0], acc[1], acc[2], acc[3]);
    op[1] = make_float4(acc[4], acc[5], acc[6], acc[7]);
}

extern "C" void kernel_launch(void* const* d_in, const int* in_sizes, int n_in,
                              void* d_out, int out_size, void* d_ws, size_t ws_size,
                              hipStream_t stream)
{
    const float* x    = (const float*)d_in[0];
    const int*   esrc = (const int*)  d_in[1];
    const int*   edst = (const int*)  d_in[2];
    const float* ew   = (const float*)d_in[3];
    const float* W1   = (const float*)d_in[4];
    const float* b1   = (const float*)d_in[5];
    const float* W2   = (const float*)d_in[6];
    const float* b2   = (const float*)d_in[7];
    const float* W3   = (const float*)d_in[8];
    const float* b3   = (const float*)d_in[9];

    const int N = in_sizes[0] / 256;   // 100000
    const int E = in_sizes[1];         // 1600000

    // workspace layout (all offsets keep >=8B alignment)
    unsigned short* Sb = (unsigned short*)d_ws;            // N*128 bf16 support
    float* H   = (float*)(Sb + (size_t)N * 128);           // N*128 fp32 hidden
    unsigned short* WT1 = (unsigned short*)(H + (size_t)N * 128);  // 128*256
    unsigned short* WT2 = WT1 + 256 * 128;                 // 64*128
    unsigned short* WT3 = WT2 + 128 * 64;                  // 64*64
    uint2* ecsr = (uint2*)(WT3 + 64 * 64);                 // E packed (src, w)
    int* deg    = (int*)(ecsr + E);                        // N
    int* offs   = deg + N;                                 // N+1 (pad 4)
    int* cursor = offs + N + 4;                            // N
    int* bsum   = cursor + N;                              // 512
    float* out  = (float*)d_out;

    const dim3 blk(256);
    const int nblkN = (N + 255) / 256;
    const int nblkE = (E + 255) / 256;
    const int mblocks = (N + 63) / 64;

    // ---- prep: weight transpose/convert + CSR build ----
    wt_kernel<<<(45056 + 255) / 256, blk, 0, stream>>>(W1, W2, W3, WT1, WT2, WT3);
    zero_int_kernel<<<nblkN, blk, 0, stream>>>(deg, N);
    hist_kernel<<<nblkE, blk, 0, stream>>>(edst, deg, E);
    scan1_kernel<<<nblkN, blk, 0, stream>>>(deg, offs, bsum, N);
    scan2_kernel<<<1, 512, 0, stream>>>(bsum, nblkN);
    scan3_kernel<<<nblkN, blk, 0, stream>>>(offs, bsum, cursor, N, E);
    fill_kernel<<<nblkE, blk, 0, stream>>>(esrc, edst, ew, cursor, ecsr, E);

    // ---- layer 1: 256 -> 128 ----
    mfma_gemm_kernel<128><<<mblocks, blk, 0, stream>>>(x, WT1, Sb, N, 256);
    gather_agg_kernel<128, 4, true><<<((N * 16) + 255) / 256, blk, 0, stream>>>(
        Sb, offs, ecsr, b1, H, N);

    // ---- layer 2: 128 -> 64 ----
    mfma_gemm_kernel<64><<<mblocks, blk, 0, stream>>>(H, WT2, Sb, N, 128);
    gather_agg_kernel<64, 3, true><<<((N * 8) + 255) / 256, blk, 0, stream>>>(
        Sb, offs, ecsr, b2, H, N);

    // ---- layer 3: 64 -> 64 ----
    mfma_gemm_kernel<64><<<mblocks, blk, 0, stream>>>(H, WT3, Sb, N, 64);
    gather_agg_kernel<64, 3, false><<<((N * 8) + 255) / 256, blk, 0, stream>>>(
        Sb, offs, ecsr, b3, out, N);
}